// Round 6
// baseline (935.498 us; speedup 1.0000x reference)
//
#include <hip/hip_runtime.h>
#include <hip/hip_bf16.h>
#include <cmath>

typedef __attribute__((ext_vector_type(8))) short short8;
typedef __attribute__((ext_vector_type(4))) float f32x4;
typedef unsigned short u16;

#define HW 9216   // 96*96

__device__ inline float bf2f(u16 u) {
    union { unsigned int i; float f; } x; x.i = ((unsigned int)u) << 16; return x.f;
}
__device__ inline u16 f2bf(float f) {
    union { unsigned int i; float f; } x; x.f = f;
    unsigned int r = x.i + 0x7FFF + ((x.i >> 16) & 1);
    return (u16)(r >> 16);
}

// ---------------------------------------------------------------------------
// Weight transform (fp32 -> bf16):
//   w_red [128,256,3,3] -> Wt1 [128][2304], k=(kh*3+kw)*256+ci
//   w_la2 [128,16,3,3]  -> Wt2 [128][160],  k=(kh*3+kw)*16+ci, zero pad 144..159
// ---------------------------------------------------------------------------
__global__ __launch_bounds__(256) void transform_w(
    const float* __restrict__ wred, const float* __restrict__ wla2,
    u16* __restrict__ Wt1, u16* __restrict__ Wt2)
{
    int idx = blockIdx.x * 256 + threadIdx.x;
    if (idx < 128 * 2304) {
        int co = idx / 2304;
        int rem = idx - co * 2304;
        int khw = rem >> 8, ci = rem & 255;
        Wt1[idx] = f2bf(wred[((co << 8) + ci) * 9 + khw]);
    } else {
        int i2 = idx - 128 * 2304;
        if (i2 < 128 * 160) {
            int co = i2 / 160;
            int k = i2 - co * 160;
            int khw = k >> 4, ci = k & 15;
            Wt2[i2] = (khw < 9) ? f2bf(wla2[((co << 4) + ci) * 9 + khw]) : (u16)0;
        }
    }
}

// ---------------------------------------------------------------------------
// Implicit-GEMM 3x3 SAME conv via MFMA 16x16x32 bf16.
// C[co(128)][p(128)] per block; pixel tile = 32w x 4h; grid (72, B).
// CIN==256: input = fp32 x (converted in-register). CIN==16: input = bf16 buffer.
// EPI==1: BN+SiLU -> bf16 OutH (xr).
// EPI==2: out = xr + ctx*(1+tanh(acc)) -> fp32 OutF (ctx read fp32, same slot).
// D decode (HW-verified rounds 2/4/5): co = quad*4+reg within subtile (A-free),
// pixel = lane&15 (B-free).
// ---------------------------------------------------------------------------
template<int CIN, int KTILES, int KP, int EPI>
__global__ __launch_bounds__(256) void conv_k(
    const float* __restrict__ Xf, const u16* __restrict__ Xh,
    const u16* __restrict__ Wt,
    u16* OutH, float* OutF,
    const float* __restrict__ bg, const float* __restrict__ bb,
    const float* __restrict__ bm, const float* __restrict__ bv,
    const u16* __restrict__ xrb, const float* ctxf)
{
    __shared__ __align__(16) short As[128 * 32];
    __shared__ __align__(16) short Bs[128 * 32];
    __shared__ float invA[128], betA[128];

    const int tid = threadIdx.x;
    const int b = blockIdx.y;
    const int tile = blockIdx.x;
    const int w0 = (tile % 3) * 32;
    const int h0 = (tile / 3) * 4;

    const int lane = tid & 63;
    const int wid = tid >> 6;
    const int wm = (wid & 1) * 64;   // m (co) offset of this wave
    const int wn = (wid >> 1) * 64;  // n (pixel) offset
    const int r = lane & 15;
    const int quad = lane >> 4;

    if constexpr (EPI == 1) {
        if (tid < 128) {
            float iv = bg[tid] * rsqrtf(bv[tid] + 1e-5f);
            invA[tid] = iv;
            betA[tid] = bb[tid] - bm[tid] * iv;
        }
    }

    // staging assignments (512 slots of 8 contiguous k each, 2 per thread)
    const int p = tid & 127;        // B: pixel row in tile
    const int o_lo = tid >> 7;      // slots o_lo and o_lo+2
    const int pw = p & 31, ph = p >> 5;
    const int hg = h0 + ph, wg = w0 + pw;
    const int co_s = tid & 127;     // A: co row

    f32x4 acc[4][4];
    f32x4 zz = {0.f, 0.f, 0.f, 0.f};
#pragma unroll
    for (int i = 0; i < 4; i++)
#pragma unroll
        for (int j = 0; j < 4; j++) acc[i][j] = zz;

    for (int kt = 0; kt < KTILES; ++kt) {
        // ---- stage A (weights, contiguous bf16 copy)
#pragma unroll
        for (int s = 0; s < 2; ++s) {
            int o = o_lo + s * 2;
            short8 wv8 = *(const short8*)(Wt + (size_t)co_s * KP + kt * 32 + o * 8);
            *(short8*)(As + co_s * 32 + o * 8) = wv8;
        }
        // ---- stage B (im2col gather with zero padding)
#pragma unroll
        for (int s = 0; s < 2; ++s) {
            int o = o_lo + s * 2;
            int khw, ci0;
            if (CIN == 256) { khw = kt >> 3; ci0 = (kt & 7) * 32 + o * 8; }
            else            { int kg = kt * 32 + o * 8; khw = kg >> 4; ci0 = kg & 15; }
            int dh = (khw * 11) >> 5;       // khw/3 for khw in [0,9]
            int dw = khw - 3 * dh;
            int hh = hg + dh - 1, ww = wg + dw - 1;
            bool ok = ((unsigned)hh < 96u) && ((unsigned)ww < 96u) && (CIN == 256 || khw < 9);
            short8 vv;
            if (CIN == 256) {
                const float* src = Xf + (size_t)b * CIN * HW + (size_t)ci0 * HW + hh * 96 + ww;
#pragma unroll
                for (int j = 0; j < 8; ++j)
                    vv[j] = ok ? (short)f2bf(src[j * HW]) : (short)0;
            } else {
                const u16* src = Xh + (size_t)b * CIN * HW + (size_t)ci0 * HW + hh * 96 + ww;
#pragma unroll
                for (int j = 0; j < 8; ++j)
                    vv[j] = ok ? (short)src[j * HW] : (short)0;
            }
            *(short8*)(Bs + p * 32 + o * 8) = vv;
        }
        __syncthreads();
        short8 af[4], bfr[4];
#pragma unroll
        for (int i = 0; i < 4; i++)
            af[i] = *(const short8*)(As + (wm + i * 16 + r) * 32 + quad * 8);
#pragma unroll
        for (int j = 0; j < 4; j++)
            bfr[j] = *(const short8*)(Bs + (wn + j * 16 + r) * 32 + quad * 8);
#pragma unroll
        for (int i = 0; i < 4; i++)
#pragma unroll
            for (int j = 0; j < 4; j++)
                acc[i][j] = __builtin_amdgcn_mfma_f32_16x16x32_bf16(af[i], bfr[j], acc[i][j], 0, 0, 0);
        __syncthreads();
    }

    // ---- epilogue (verified decode): co = wm+i*16+quad*4+g ; pixel = wn+j*16+r
#pragma unroll
    for (int i = 0; i < 4; i++) {
#pragma unroll
        for (int j = 0; j < 4; j++) {
            int pl = wn + j * 16 + r;
            int w = w0 + (pl & 31), h = h0 + (pl >> 5);
#pragma unroll
            for (int g = 0; g < 4; ++g) {
                int co = wm + i * 16 + quad * 4 + g;
                float v = acc[i][j][g];
                size_t oidx = ((size_t)b * 128 + co) * HW + h * 96 + w;
                if constexpr (EPI == 1) {
                    float val = v * invA[co] + betA[co];
                    float sv = val / (1.f + __expf(-val));   // SiLU
                    OutH[oidx] = f2bf(sv);
                } else {
                    float xv = bf2f(xrb[oidx]);
                    float cv = ctxf[oidx];                   // fp32 ctx, same slot
                    float e = __expf(2.f * v);
                    float th = 1.f - 2.f / (e + 1.f);        // tanh
                    OutF[oidx] = xv + cv * (1.f + th);       // fp32 final output
                }
            }
        }
    }
}

// ---------------------------------------------------------------------------
// Per-batch prep: 8 tokens (16x16 means of xr) -> k,v -> folded A = w_q^T k, c0 = b_q.k
// grid = B blocks, 256 threads. Weights read as fp32.
// ---------------------------------------------------------------------------
__global__ __launch_bounds__(256) void prep_attn(
    const u16* __restrict__ xr,
    const float* __restrict__ wk, const float* __restrict__ bk,
    const float* __restrict__ wv, const float* __restrict__ bv,
    const float* __restrict__ wq, const float* __restrict__ bq,
    float* __restrict__ Aout, float* __restrict__ Vout, float* __restrict__ c0out)
{
    __shared__ float toks[8 * 128];
    __shared__ float part[256];
    __shared__ float ks[8 * 32];
    int t = threadIdx.x;
    int b = blockIdx.x;
    int c = t & 127, half = t >> 7;
    const u16* xb = xr + (size_t)b * 128 * HW + (size_t)c * HW;

    for (int n = 0; n < 8; ++n) {
        int i0 = (n < 6) ? 0 : 16;
        int j0 = (n < 6) ? n * 16 : (n - 6) * 16;
        float s = 0.f;
        for (int rr = 0; rr < 8; ++rr) {
            int row = i0 + half * 8 + rr;
            const u16* rp = xb + row * 96 + j0;
#pragma unroll
            for (int jj = 0; jj < 16; ++jj) s += bf2f(rp[jj]);
        }
        part[t] = s;
        __syncthreads();
        if (t < 128) toks[n * 128 + t] = (part[t] + part[t + 128]) * (1.f / 256.f);
        __syncthreads();
    }
    {
        int n = t >> 5, d = t & 31;
        float s = bk[d];
        for (int cc = 0; cc < 128; ++cc) s += wk[d * 128 + cc] * toks[n * 128 + cc];
        ks[n * 32 + d] = s;
    }
    for (int i = 0; i < 4; ++i) {
        int q = t + i * 256;
        int n = q >> 7, cc = q & 127;
        float s = bv[cc];
        for (int c2 = 0; c2 < 128; ++c2) s += wv[cc * 128 + c2] * toks[n * 128 + c2];
        Vout[((size_t)b * 8 + n) * 128 + cc] = s;
    }
    __syncthreads();
    for (int i = 0; i < 4; ++i) {
        int q = t + i * 256;
        int n = q >> 7, cc = q & 127;
        float s = 0.f;
        for (int d = 0; d < 32; ++d) s += wq[d * 128 + cc] * ks[n * 32 + d];
        Aout[((size_t)b * 8 + n) * 128 + cc] = s;
    }
    if (t < 8) {
        float s = 0.f;
        for (int d = 0; d < 32; ++d) s += bq[d] * ks[t * 32 + d];
        c0out[b * 8 + t] = s;
    }
}

// ---------------------------------------------------------------------------
// Fused attention + LocalAtten 1x1 branch. 64 pixels / block, grid (144, B).
// s = A.xr + c0 -> softmax(8) -> ctx = att.V (fp32 to d_out) -> y = SiLU(BN(Wla1.ctx))
// ---------------------------------------------------------------------------
__global__ __launch_bounds__(256) void attn_k(
    const u16* __restrict__ xr,
    const float* __restrict__ Ain, const float* __restrict__ Vin,
    const float* __restrict__ c0in,
    const float* __restrict__ wla1,
    const float* __restrict__ lag, const float* __restrict__ lab,
    const float* __restrict__ lam, const float* __restrict__ lav,
    float* __restrict__ ctxout, u16* __restrict__ yout)
{
    __shared__ float Xs[128 * 64];       // xr tile, later reused for ctx
    __shared__ float As[8 * 128], Vs[8 * 128], Ws[16 * 128];
    __shared__ float satt[8 * 64];
    __shared__ float c0s[8], inv1[16], bet1[16];

    int t = threadIdx.x;
    int b = blockIdx.y;
    int p0 = blockIdx.x * 64;

    for (int i = t; i < 1024; i += 256) { As[i] = Ain[b * 1024 + i]; Vs[i] = Vin[b * 1024 + i]; }
    for (int i = t; i < 2048; i += 256) Ws[i] = wla1[i];
    if (t < 8) c0s[t] = c0in[b * 8 + t];
    if (t < 16) {
        float iv = lag[t] * rsqrtf(lav[t] + 1e-5f);
        inv1[t] = iv; bet1[t] = lab[t] - lam[t] * iv;
    }
    const u16* xb = xr + (size_t)b * 128 * HW + p0;
    for (int i = 0; i < 32; ++i) {
        int idx = t + i * 256;
        int c = idx >> 6, pp = idx & 63;
        Xs[c * 64 + pp] = bf2f(xb[(size_t)c * HW + pp]);
    }
    __syncthreads();
    {
        int pp = t & 63, ng = t >> 6;
        float a0 = 0.f, a1 = 0.f;
        for (int c = 0; c < 128; ++c) {
            float x = Xs[c * 64 + pp];
            a0 += As[(ng * 2) * 128 + c] * x;
            a1 += As[(ng * 2 + 1) * 128 + c] * x;
        }
        satt[(ng * 2) * 64 + pp] = a0 + c0s[ng * 2];
        satt[(ng * 2 + 1) * 64 + pp] = a1 + c0s[ng * 2 + 1];
    }
    __syncthreads();
    if (t < 64) {
        float m = -1e30f;
        float sv[8];
#pragma unroll
        for (int n = 0; n < 8; ++n) { sv[n] = satt[n * 64 + t]; m = fmaxf(m, sv[n]); }
        float sum = 0.f;
#pragma unroll
        for (int n = 0; n < 8; ++n) { sv[n] = __expf(sv[n] - m); sum += sv[n]; }
        float rcp = 1.f / sum;
#pragma unroll
        for (int n = 0; n < 8; ++n) satt[n * 64 + t] = sv[n] * rcp;
    }
    __syncthreads();
    {
        int pp = t & 63, cg = t >> 6;
        float at[8];
#pragma unroll
        for (int n = 0; n < 8; ++n) at[n] = satt[n * 64 + pp];
        for (int ci = 0; ci < 32; ++ci) {
            int c = cg * 32 + ci;
            float s = 0.f;
#pragma unroll
            for (int n = 0; n < 8; ++n) s += at[n] * Vs[n * 128 + c];
            ctxout[((size_t)b * 128 + c) * HW + p0 + pp] = s;   // fp32
            Xs[c * 64 + pp] = s;
        }
    }
    __syncthreads();
    {
        int pp = t & 63, dg = t >> 6;
        float a[4] = {0.f, 0.f, 0.f, 0.f};
        for (int c = 0; c < 128; ++c) {
            float x = Xs[c * 64 + pp];
#pragma unroll
            for (int k = 0; k < 4; ++k) a[k] += Ws[(dg * 4 + k) * 128 + c] * x;
        }
#pragma unroll
        for (int k = 0; k < 4; ++k) {
            int d = dg * 4 + k;
            float val = a[k] * inv1[d] + bet1[d];
            float s = val / (1.f + __expf(-val));
            yout[((size_t)b * 16 + d) * HW + p0 + pp] = f2bf(s);
        }
    }
}

// ---------------------------------------------------------------------------
extern "C" void kernel_launch(void* const* d_in, const int* in_sizes, int n_in,
                              void* d_out, int out_size, void* d_ws, size_t ws_size,
                              hipStream_t stream)
{
    const float* x    = (const float*)d_in[0];
    const float* wred = (const float*)d_in[1];
    const float* bng  = (const float*)d_in[2];
    const float* bnb  = (const float*)d_in[3];
    const float* bnm  = (const float*)d_in[4];
    const float* bnv  = (const float*)d_in[5];
    const float* wq   = (const float*)d_in[6];
    const float* bq   = (const float*)d_in[7];
    const float* wk   = (const float*)d_in[8];
    const float* bk   = (const float*)d_in[9];
    const float* wv   = (const float*)d_in[10];
    const float* bv   = (const float*)d_in[11];
    // d_in[12] = lsh: provably unused (permutation-invariance of softmax attention)
    const float* wla1 = (const float*)d_in[13];
    const float* lag  = (const float*)d_in[14];
    const float* lab  = (const float*)d_in[15];
    const float* lam  = (const float*)d_in[16];
    const float* lav  = (const float*)d_in[17];
    const float* wla2 = (const float*)d_in[18];

    char* ws = (char*)d_ws;
    u16*   xr  = (u16*)(ws + 0);            // 18,874,368 B
    u16*   yb  = (u16*)(ws + 18874368);     //  2,359,296 B
    u16*   Wt1 = (u16*)(ws + 21233664);     //    589,824 B
    u16*   Wt2 = (u16*)(ws + 21823488);     //     40,960 B
    float* Ab  = (float*)(ws + 21864448);   //     32,768 B
    float* Vb  = (float*)(ws + 21897216);   //     32,768 B
    float* c0b = (float*)(ws + 21929984);   //        256 B
    float* outp = (float*)d_out;            // fp32: ctx staged here, then final out

    transform_w<<<dim3(1232), dim3(256), 0, stream>>>(wred, wla2, Wt1, Wt2);

    conv_k<256, 72, 2304, 1><<<dim3(72, 8), dim3(256), 0, stream>>>(
        x, nullptr, Wt1, xr, nullptr, bng, bnb, bnm, bnv, nullptr, nullptr);

    prep_attn<<<dim3(8), dim3(256), 0, stream>>>(xr, wk, bk, wv, bv, wq, bq, Ab, Vb, c0b);

    attn_k<<<dim3(144, 8), dim3(256), 0, stream>>>(
        xr, Ab, Vb, c0b, wla1, lag, lab, lam, lav, outp, yb);

    conv_k<16, 5, 160, 2><<<dim3(72, 8), dim3(256), 0, stream>>>(
        nullptr, yb, Wt2, nullptr, outp, nullptr, nullptr, nullptr, nullptr, xr, outp);
}

// Round 8
// 408.367 us; speedup vs baseline: 2.2908x; 2.2908x over previous
//
#include <hip/hip_runtime.h>
#include <hip/hip_bf16.h>
#include <cmath>

typedef __attribute__((ext_vector_type(8))) short short8;
typedef __attribute__((ext_vector_type(4))) short s16x4;
typedef __attribute__((ext_vector_type(4))) float f32x4;
typedef unsigned short u16;

#define HW 9216   // 96*96

__device__ inline float bf2f(u16 u) {
    union { unsigned int i; float f; } x; x.i = ((unsigned int)u) << 16; return x.f;
}
__device__ inline u16 f2bf(float f) {
    union { unsigned int i; float f; } x; x.f = f;
    unsigned int r = x.i + 0x7FFF + ((x.i >> 16) & 1);
    return (u16)(r >> 16);
}

// ---------------------------------------------------------------------------
// Weight transform (fp32 -> bf16):
//   w_red [128,256,3,3] -> Wt1 [128][2304], k = c*288 + khw*32 + ciL  (ci-chunk major!)
//   w_la2 [128,16,3,3]  -> Wt2 [128][160],  k = khw*16 + ci, zero pad 144..159
// ---------------------------------------------------------------------------
__global__ __launch_bounds__(256) void transform_w(
    const float* __restrict__ wred, const float* __restrict__ wla2,
    u16* __restrict__ Wt1, u16* __restrict__ Wt2)
{
    int idx = blockIdx.x * 256 + threadIdx.x;
    if (idx < 128 * 2304) {
        int co = idx / 2304;
        int rem = idx - co * 2304;
        int c = rem / 288;
        int r2 = rem - c * 288;
        int khw = r2 >> 5, ciL = r2 & 31;
        Wt1[idx] = f2bf(wred[((co * 256 + c * 32 + ciL) * 9 + khw)]);
    } else {
        int i2 = idx - 128 * 2304;
        if (i2 < 128 * 160) {
            int co = i2 / 160;
            int k = i2 - co * 160;
            int khw = k >> 4, ci = k & 15;
            Wt2[i2] = (khw < 9) ? f2bf(wla2[((co << 4) + ci) * 9 + khw]) : (u16)0;
        }
    }
}

// ---------------------------------------------------------------------------
// x [b][ci][p] fp32 -> xt [b][p][ci] bf16 (NHWC). Grid 288 (b = bid&7).
// Reads coalesced per (oct,j); writes 16 B per thread, block covers the full
// 128 KB pixel-chunk so L2 lines are fully written.
// ---------------------------------------------------------------------------
__global__ __launch_bounds__(256) void transpose_x(
    const float* __restrict__ X, u16* __restrict__ Xt)
{
    int bid = blockIdx.x;
    int b = bid & 7, chunk = bid >> 3;           // 36 chunks of 256 px
    int p = chunk * 256 + threadIdx.x;
    const float* xb = X + (size_t)b * 256 * HW + p;
    u16* ot = Xt + ((size_t)b * HW + p) * 256;
    for (int oct = 0; oct < 32; ++oct) {
        short8 v;
#pragma unroll
        for (int j = 0; j < 8; ++j)
            v[j] = (short)f2bf(xb[(size_t)(oct * 8 + j) * HW]);
        *(short8*)(ot + oct * 8) = v;
    }
}

// ---------------------------------------------------------------------------
// Implicit-GEMM 3x3 SAME conv via MFMA 16x16x32 bf16, NHWC bf16 input.
// C[co(128)][p(128)] per block; pixel tile = 32w x 4h; grid 576 1-D
// (b = bid&7 -> XCD-batch locality, tile = bid>>3).
// CIN==256: K-order = c-major (c = kt/9, khw = kt%9), xt stride 256.
// CIN==16 : K-order = khw-major (kg = kt*32+o*8), yt stride 16.
// EPI==1: BN+SiLU -> bf16 OutH (xr).  EPI==2: out = xr + ctx*(1+tanh) -> fp32.
// LDS rows padded to 40 shorts (80 B) to spread ds_read_b128 bank groups.
// ---------------------------------------------------------------------------
template<int CIN, int KTILES, int KP, int EPI>
__global__ __launch_bounds__(256) void conv_k(
    const u16* __restrict__ Xt, const u16* __restrict__ Wt,
    u16* OutH, float* OutF,
    const float* __restrict__ bg, const float* __restrict__ bb,
    const float* __restrict__ bm, const float* __restrict__ bv,
    const u16* __restrict__ xrb, const float* ctxf)
{
    const int LDB = 40;
    __shared__ __align__(16) short As[128 * 40];
    __shared__ __align__(16) short Bs[128 * 40];
    __shared__ float invA[128], betA[128];

    const int tid = threadIdx.x;
    const int bid = blockIdx.x;
    const int b = bid & 7;
    const int tile = bid >> 3;
    const int w0 = (tile % 3) * 32;
    const int h0 = (tile / 3) * 4;

    const int lane = tid & 63;
    const int wid = tid >> 6;
    const int wm = (wid & 1) * 64;   // m (co) offset of this wave
    const int wn = (wid >> 1) * 64;  // n (pixel) offset
    const int r = lane & 15;
    const int quad = lane >> 4;

    if constexpr (EPI == 1) {
        if (tid < 128) {
            float iv = bg[tid] * rsqrtf(bv[tid] + 1e-5f);
            invA[tid] = iv;
            betA[tid] = bb[tid] - bm[tid] * iv;
        }
    }

    // staging assignments (512 slots of 8 contiguous k each, 2 per thread)
    const int p = tid & 127;        // B: pixel row in tile / A: co row
    const int o_lo = tid >> 7;      // slots o_lo and o_lo+2
    const int pw = p & 31, ph = p >> 5;
    const int hg = h0 + ph, wg = w0 + pw;

    const u16* XtB = Xt + (size_t)b * HW * CIN;
    const short8 z8 = {0, 0, 0, 0, 0, 0, 0, 0};

    f32x4 acc[4][4];
    f32x4 zz = {0.f, 0.f, 0.f, 0.f};
#pragma unroll
    for (int i = 0; i < 4; i++)
#pragma unroll
        for (int j = 0; j < 4; j++) acc[i][j] = zz;

    for (int kt = 0; kt < KTILES; ++kt) {
        // ---- stage A (weights, contiguous bf16 copy)
#pragma unroll
        for (int s = 0; s < 2; ++s) {
            int o = o_lo + s * 2;
            short8 wv8 = *(const short8*)(Wt + (size_t)p * KP + kt * 32 + o * 8);
            *(short8*)(As + p * LDB + o * 8) = wv8;
        }
        // ---- stage B (NHWC gather: one 16-B load per slot)
        if (CIN == 256) {
            int c = (kt * 57) >> 9;          // kt/9
            int khw = kt - c * 9;
            int dh = (khw * 11) >> 5;        // khw/3
            int dw = khw - 3 * dh;
            int hh = hg + dh - 1, ww = wg + dw - 1;
            bool ok = ((unsigned)hh < 96u) && ((unsigned)ww < 96u);
            const u16* src = XtB + ((size_t)hh * 96 + ww) * 256 + c * 32;
#pragma unroll
            for (int s = 0; s < 2; ++s) {
                int o = o_lo + s * 2;
                short8 vv = ok ? *(const short8*)(src + o * 8) : z8;
                *(short8*)(Bs + p * LDB + o * 8) = vv;
            }
        } else {
#pragma unroll
            for (int s = 0; s < 2; ++s) {
                int o = o_lo + s * 2;
                int kg = kt * 32 + o * 8;
                int khw = kg >> 4, ci0 = kg & 15;
                int dh = (khw * 11) >> 5;
                int dw = khw - 3 * dh;
                int hh = hg + dh - 1, ww = wg + dw - 1;
                bool ok = ((unsigned)hh < 96u) && ((unsigned)ww < 96u) && (khw < 9);
                const u16* src = XtB + ((size_t)hh * 96 + ww) * 16 + ci0;
                short8 vv = ok ? *(const short8*)src : z8;
                *(short8*)(Bs + p * LDB + o * 8) = vv;
            }
        }
        __syncthreads();
        short8 af[4], bfr[4];
#pragma unroll
        for (int i = 0; i < 4; i++)
            af[i] = *(const short8*)(As + (wm + i * 16 + r) * LDB + quad * 8);
#pragma unroll
        for (int j = 0; j < 4; j++)
            bfr[j] = *(const short8*)(Bs + (wn + j * 16 + r) * LDB + quad * 8);
#pragma unroll
        for (int i = 0; i < 4; i++)
#pragma unroll
            for (int j = 0; j < 4; j++)
                acc[i][j] = __builtin_amdgcn_mfma_f32_16x16x32_bf16(af[i], bfr[j], acc[i][j], 0, 0, 0);
        __syncthreads();
    }

    // ---- epilogue (HW-verified decode): co = wm+i*16+quad*4+g ; pixel = wn+j*16+r
#pragma unroll
    for (int i = 0; i < 4; i++) {
#pragma unroll
        for (int j = 0; j < 4; j++) {
            int pl = wn + j * 16 + r;
            int w = w0 + (pl & 31), h = h0 + (pl >> 5);
#pragma unroll
            for (int g = 0; g < 4; ++g) {
                int co = wm + i * 16 + quad * 4 + g;
                float v = acc[i][j][g];
                size_t oidx = ((size_t)b * 128 + co) * HW + h * 96 + w;
                if constexpr (EPI == 1) {
                    float val = v * invA[co] + betA[co];
                    float sv = val / (1.f + __expf(-val));   // SiLU
                    OutH[oidx] = f2bf(sv);
                } else {
                    float xv = bf2f(xrb[oidx]);
                    float cv = ctxf[oidx];                   // fp32 ctx, same slot
                    float e = __expf(2.f * v);
                    float th = 1.f - 2.f / (e + 1.f);        // tanh
                    OutF[oidx] = xv + cv * (1.f + th);       // fp32 final output
                }
            }
        }
    }
}

// ---------------------------------------------------------------------------
// Per-(batch, token) prep: token = 16x16 mean of xr -> k -> V row, folded A row,
// c0. Grid 64 (b = bid&7, n = bid>>3), 256 threads. Tokens are independent.
// ---------------------------------------------------------------------------
__global__ __launch_bounds__(256) void prep_attn(
    const u16* __restrict__ xr,
    const float* __restrict__ wk, const float* __restrict__ bk,
    const float* __restrict__ wv, const float* __restrict__ bv,
    const float* __restrict__ wq, const float* __restrict__ bq,
    float* __restrict__ Aout, float* __restrict__ Vout, float* __restrict__ c0out)
{
    __shared__ float part[256];
    __shared__ float tok[128];
    __shared__ float ks[32];
    int t = threadIdx.x;
    int bid = blockIdx.x;
    int b = bid & 7, n = bid >> 3;
    int c = t & 127, half = t >> 7;
    int i0 = (n < 6) ? 0 : 16;
    int j0 = ((n < 6) ? n : (n - 6)) * 16;
    const u16* xb = xr + (size_t)(b * 128 + c) * HW;

    float s = 0.f;
    for (int rr = 0; rr < 8; ++rr) {
        int row = i0 + half * 8 + rr;
        const u16* rp = xb + row * 96 + j0;
        short8 v0 = *(const short8*)rp;
        short8 v1 = *(const short8*)(rp + 8);
#pragma unroll
        for (int j = 0; j < 8; ++j) s += bf2f((u16)v0[j]) + bf2f((u16)v1[j]);
    }
    part[t] = s;
    __syncthreads();
    if (t < 128) tok[t] = (part[t] + part[t + 128]) * (1.f / 256.f);
    __syncthreads();
    if (t < 32) {
        float s2 = bk[t];
        for (int cc = 0; cc < 128; ++cc) s2 += wk[t * 128 + cc] * tok[cc];
        ks[t] = s2;
    }
    __syncthreads();
    if (t < 128) {
        float s3 = bv[c];
        for (int c2 = 0; c2 < 128; ++c2) s3 += wv[c * 128 + c2] * tok[c2];
        Vout[((size_t)b * 8 + n) * 128 + c] = s3;
    } else {
        float s4 = 0.f;
        for (int d = 0; d < 32; ++d) s4 += wq[d * 128 + c] * ks[d];
        Aout[((size_t)b * 8 + n) * 128 + c] = s4;
    }
    if (t == 0) {
        float s5 = 0.f;
        for (int d = 0; d < 32; ++d) s5 += bq[d] * ks[d];
        c0out[b * 8 + n] = s5;
    }
}

// ---------------------------------------------------------------------------
// Fused attention + LocalAtten 1x1 branch. 64 px/block, grid 1152 1-D
// (b = bid&7). ctx -> fp32 d_out; y -> NHWC-16 bf16 (for conv2 staging).
// ---------------------------------------------------------------------------
__global__ __launch_bounds__(256) void attn_k(
    const u16* __restrict__ xr,
    const float* __restrict__ Ain, const float* __restrict__ Vin,
    const float* __restrict__ c0in,
    const float* __restrict__ wla1,
    const float* __restrict__ lag, const float* __restrict__ lab,
    const float* __restrict__ lam, const float* __restrict__ lav,
    float* __restrict__ ctxout, u16* __restrict__ yout)
{
    __shared__ float Xs[128 * 64];       // xr tile, later reused for ctx
    __shared__ float As[8 * 128], Vs[8 * 128], Ws[16 * 128];
    __shared__ float satt[8 * 64];
    __shared__ float c0s[8], inv1[16], bet1[16];

    int t = threadIdx.x;
    int bid = blockIdx.x;
    int b = bid & 7;
    int p0 = (bid >> 3) * 64;

    for (int i = t; i < 1024; i += 256) { As[i] = Ain[b * 1024 + i]; Vs[i] = Vin[b * 1024 + i]; }
    for (int i = t; i < 2048; i += 256) Ws[i] = wla1[i];
    if (t < 8) c0s[t] = c0in[b * 8 + t];
    if (t < 16) {
        float iv = lag[t] * rsqrtf(lav[t] + 1e-5f);
        inv1[t] = iv; bet1[t] = lab[t] - lam[t] * iv;
    }
    const u16* xb = xr + (size_t)b * 128 * HW + p0;
    // vectorized Xs fill: 128 c-rows x 64 px, short8 per (c, seg)
#pragma unroll
    for (int it = 0; it < 4; ++it) {
        int c = (t >> 3) + it * 32;
        int seg = t & 7;
        short8 v = *(const short8*)(xb + (size_t)c * HW + seg * 8);
#pragma unroll
        for (int j = 0; j < 8; ++j) Xs[c * 64 + seg * 8 + j] = bf2f((u16)v[j]);
    }
    __syncthreads();
    {
        int pp = t & 63, ng = t >> 6;
        float a0 = 0.f, a1 = 0.f;
        for (int c = 0; c < 128; ++c) {
            float x = Xs[c * 64 + pp];
            a0 += As[(ng * 2) * 128 + c] * x;
            a1 += As[(ng * 2 + 1) * 128 + c] * x;
        }
        satt[(ng * 2) * 64 + pp] = a0 + c0s[ng * 2];
        satt[(ng * 2 + 1) * 64 + pp] = a1 + c0s[ng * 2 + 1];
    }
    __syncthreads();
    if (t < 64) {
        float m = -1e30f;
        float sv[8];
#pragma unroll
        for (int n = 0; n < 8; ++n) { sv[n] = satt[n * 64 + t]; m = fmaxf(m, sv[n]); }
        float sum = 0.f;
#pragma unroll
        for (int n = 0; n < 8; ++n) { sv[n] = __expf(sv[n] - m); sum += sv[n]; }
        float rcp = 1.f / sum;
#pragma unroll
        for (int n = 0; n < 8; ++n) satt[n * 64 + t] = sv[n] * rcp;
    }
    __syncthreads();
    {
        int pp = t & 63, cg = t >> 6;
        float at[8];
#pragma unroll
        for (int n = 0; n < 8; ++n) at[n] = satt[n * 64 + pp];
        for (int ci = 0; ci < 32; ++ci) {
            int c = cg * 32 + ci;
            float s = 0.f;
#pragma unroll
            for (int n = 0; n < 8; ++n) s += at[n] * Vs[n * 128 + c];
            ctxout[((size_t)b * 128 + c) * HW + p0 + pp] = s;   // fp32
            Xs[c * 64 + pp] = s;
        }
    }
    __syncthreads();
    {
        int pp = t & 63, dg = t >> 6;
        float a[4] = {0.f, 0.f, 0.f, 0.f};
        for (int c = 0; c < 128; ++c) {
            float x = Xs[c * 64 + pp];
#pragma unroll
            for (int k = 0; k < 4; ++k) a[k] += Ws[(dg * 4 + k) * 128 + c] * x;
        }
        s16x4 pk;
#pragma unroll
        for (int k = 0; k < 4; ++k) {
            int d = dg * 4 + k;
            float val = a[k] * inv1[d] + bet1[d];
            float s = val / (1.f + __expf(-val));
            pk[k] = (short)f2bf(s);
        }
        // y in NHWC-16: yt[b][p][d]
        *(s16x4*)(yout + ((size_t)b * HW + p0 + pp) * 16 + dg * 4) = pk;
    }
}

// ---------------------------------------------------------------------------
extern "C" void kernel_launch(void* const* d_in, const int* in_sizes, int n_in,
                              void* d_out, int out_size, void* d_ws, size_t ws_size,
                              hipStream_t stream)
{
    const float* x    = (const float*)d_in[0];
    const float* wred = (const float*)d_in[1];
    const float* bng  = (const float*)d_in[2];
    const float* bnb  = (const float*)d_in[3];
    const float* bnm  = (const float*)d_in[4];
    const float* bnv  = (const float*)d_in[5];
    const float* wq   = (const float*)d_in[6];
    const float* bq   = (const float*)d_in[7];
    const float* wk   = (const float*)d_in[8];
    const float* bk   = (const float*)d_in[9];
    const float* wv   = (const float*)d_in[10];
    const float* bv   = (const float*)d_in[11];
    // d_in[12] = lsh: provably unused (permutation-invariance of softmax attention)
    const float* wla1 = (const float*)d_in[13];
    const float* lag  = (const float*)d_in[14];
    const float* lab  = (const float*)d_in[15];
    const float* lam  = (const float*)d_in[16];
    const float* lav  = (const float*)d_in[17];
    const float* wla2 = (const float*)d_in[18];

    char* ws = (char*)d_ws;
    u16*   xr  = (u16*)(ws + 0);            // 18,874,368 B  bf16 CHW
    u16*   yt  = (u16*)(ws + 18874368);     //  2,359,296 B  bf16 NHWC-16
    u16*   Wt1 = (u16*)(ws + 21233664);     //    589,824 B
    u16*   Wt2 = (u16*)(ws + 21823488);     //     40,960 B
    float* Ab  = (float*)(ws + 21864448);   //     32,768 B
    float* Vb  = (float*)(ws + 21897216);   //     32,768 B
    float* c0b = (float*)(ws + 21929984);   //        256 B
    // xt (NHWC-256 bf16, 37,748,736 B) lives in d_out until attn_k overwrites
    // it with fp32 ctx — conv1/prep complete before that (stream-ordered).
    u16*   xt   = (u16*)d_out;
    float* outp = (float*)d_out;

    transform_w<<<dim3(1232), dim3(256), 0, stream>>>(wred, wla2, Wt1, Wt2);

    transpose_x<<<dim3(288), dim3(256), 0, stream>>>(x, xt);

    conv_k<256, 72, 2304, 1><<<dim3(576), dim3(256), 0, stream>>>(
        xt, Wt1, xr, nullptr, bng, bnb, bnm, bnv, nullptr, nullptr);

    prep_attn<<<dim3(64), dim3(256), 0, stream>>>(xr, wk, bk, wv, bv, wq, bq, Ab, Vb, c0b);

    attn_k<<<dim3(1152), dim3(256), 0, stream>>>(
        xr, Ab, Vb, c0b, wla1, lag, lab, lam, lav, outp, yt);

    conv_k<16, 5, 160, 2><<<dim3(576), dim3(256), 0, stream>>>(
        yt, Wt2, nullptr, outp, nullptr, nullptr, nullptr, nullptr, xr, outp);
}

// Round 9
// 362.691 us; speedup vs baseline: 2.5793x; 1.1259x over previous
//
#include <hip/hip_runtime.h>
#include <hip/hip_bf16.h>
#include <cmath>

typedef __attribute__((ext_vector_type(8))) short short8;
typedef __attribute__((ext_vector_type(4))) short s16x4;
typedef __attribute__((ext_vector_type(4))) float f32x4;
typedef unsigned short u16;

#define HW 9216   // 96*96

__device__ inline float bf2f(u16 u) {
    union { unsigned int i; float f; } x; x.i = ((unsigned int)u) << 16; return x.f;
}
__device__ inline u16 f2bf(float f) {
    union { unsigned int i; float f; } x; x.f = f;
    unsigned int r = x.i + 0x7FFF + ((x.i >> 16) & 1);
    return (u16)(r >> 16);
}

// ---------------------------------------------------------------------------
// Weight transform (fp32 -> bf16):
//   w_red [128,256,3,3] -> Wt1 [128][2304], k = c*288 + khw*32 + ciL  (ci-chunk major!)
//   w_la2 [128,16,3,3]  -> Wt2 [128][160],  k = khw*16 + ci, zero pad 144..159
// ---------------------------------------------------------------------------
__global__ __launch_bounds__(256) void transform_w(
    const float* __restrict__ wred, const float* __restrict__ wla2,
    u16* __restrict__ Wt1, u16* __restrict__ Wt2)
{
    int idx = blockIdx.x * 256 + threadIdx.x;
    if (idx < 128 * 2304) {
        int co = idx / 2304;
        int rem = idx - co * 2304;
        int c = rem / 288;
        int r2 = rem - c * 288;
        int khw = r2 >> 5, ciL = r2 & 31;
        Wt1[idx] = f2bf(wred[((co * 256 + c * 32 + ciL) * 9 + khw)]);
    } else {
        int i2 = idx - 128 * 2304;
        if (i2 < 128 * 160) {
            int co = i2 / 160;
            int k = i2 - co * 160;
            int khw = k >> 4, ci = k & 15;
            Wt2[i2] = (khw < 9) ? f2bf(wla2[((co << 4) + ci) * 9 + khw]) : (u16)0;
        }
    }
}

// ---------------------------------------------------------------------------
// x [b][ci][p] fp32 -> xt [b][p][ci] bf16 (NHWC). Grid 288 (b = bid&7).
// ---------------------------------------------------------------------------
__global__ __launch_bounds__(256) void transpose_x(
    const float* __restrict__ X, u16* __restrict__ Xt)
{
    int bid = blockIdx.x;
    int b = bid & 7, chunk = bid >> 3;           // 36 chunks of 256 px
    int p = chunk * 256 + threadIdx.x;
    const float* xb = X + (size_t)b * 256 * HW + p;
    u16* ot = Xt + ((size_t)b * HW + p) * 256;
    for (int oct = 0; oct < 32; ++oct) {
        short8 v;
#pragma unroll
        for (int j = 0; j < 8; ++j)
            v[j] = (short)f2bf(xb[(size_t)(oct * 8 + j) * HW]);
        *(short8*)(ot + oct * 8) = v;
    }
}

// ---------------------------------------------------------------------------
// Implicit-GEMM 3x3 SAME conv via MFMA 16x16x32 bf16, NHWC bf16 input.
// SOFTWARE-PIPELINED K-loop: register prefetch of kt+1 issued before the MFMA
// of kt; double-buffered LDS; ONE barrier per iteration. The vmcnt drain for
// the prefetch lands after the MFMA block -> global latency overlaps compute.
// C[co(128)][p(128)] per block; pixel tile 32w x 4h; grid 576 (b = bid&7).
// EPI==1: BN+SiLU -> bf16 OutH (xr).  EPI==2: out = xr + ctx*(1+tanh) -> fp32.
// ---------------------------------------------------------------------------
template<int CIN, int KTILES, int KP, int EPI>
__global__ __launch_bounds__(256) void conv_k(
    const u16* __restrict__ Xt, const u16* __restrict__ Wt,
    u16* OutH, float* OutF,
    const float* __restrict__ bg, const float* __restrict__ bb,
    const float* __restrict__ bm, const float* __restrict__ bv,
    const u16* __restrict__ xrb, const float* ctxf)
{
    const int LDB = 40;   // padded row (80 B) to spread ds_read_b128 bank groups
    __shared__ __align__(16) short As[2][128 * 40];
    __shared__ __align__(16) short Bs[2][128 * 40];
    __shared__ float invA[128], betA[128];

    const int tid = threadIdx.x;
    const int bid = blockIdx.x;
    const int b = bid & 7;
    const int tile = bid >> 3;
    const int w0 = (tile % 3) * 32;
    const int h0 = (tile / 3) * 4;

    const int lane = tid & 63;
    const int wid = tid >> 6;
    const int wm = (wid & 1) * 64;   // m (co) offset of this wave
    const int wn = (wid >> 1) * 64;  // n (pixel) offset
    const int r = lane & 15;
    const int quad = lane >> 4;

    if constexpr (EPI == 1) {
        if (tid < 128) {
            float iv = bg[tid] * rsqrtf(bv[tid] + 1e-5f);
            invA[tid] = iv;
            betA[tid] = bb[tid] - bm[tid] * iv;
        }
    }

    // staging assignments (512 slots of 8 contiguous k each, 2 per thread)
    const int p = tid & 127;        // B: pixel row in tile / A: co row
    const int o_lo = tid >> 7;      // slots o_lo and o_lo+2
    const int pw = p & 31, ph = p >> 5;
    const int hg = h0 + ph, wg = w0 + pw;

    const u16* XtB = Xt + (size_t)b * HW * CIN;
    const short8 z8 = {0, 0, 0, 0, 0, 0, 0, 0};

    short8 aR0, aR1, bR0, bR1;      // prefetch registers

    auto stage = [&](int kt) {
        aR0 = *(const short8*)(Wt + (size_t)p * KP + kt * 32 + o_lo * 8);
        aR1 = *(const short8*)(Wt + (size_t)p * KP + kt * 32 + (o_lo + 2) * 8);
        if (CIN == 256) {
            int c = (kt * 57) >> 9;          // kt/9
            int khw = kt - c * 9;
            int dh = (khw * 11) >> 5;        // khw/3
            int dw = khw - 3 * dh;
            int hh = hg + dh - 1, ww = wg + dw - 1;
            bool ok = ((unsigned)hh < 96u) && ((unsigned)ww < 96u);
            const u16* src = XtB + ((size_t)hh * 96 + ww) * 256 + c * 32;
            bR0 = ok ? *(const short8*)(src + o_lo * 8) : z8;
            bR1 = ok ? *(const short8*)(src + (o_lo + 2) * 8) : z8;
        } else {
            {
                int kg = kt * 32 + o_lo * 8;
                int khw = kg >> 4, ci0 = kg & 15;
                int dh = (khw * 11) >> 5, dw = khw - 3 * dh;
                int hh = hg + dh - 1, ww = wg + dw - 1;
                bool ok = ((unsigned)hh < 96u) && ((unsigned)ww < 96u) && (khw < 9);
                const u16* src = XtB + ((size_t)hh * 96 + ww) * 16 + ci0;
                bR0 = ok ? *(const short8*)src : z8;
            }
            {
                int kg = kt * 32 + (o_lo + 2) * 8;
                int khw = kg >> 4, ci0 = kg & 15;
                int dh = (khw * 11) >> 5, dw = khw - 3 * dh;
                int hh = hg + dh - 1, ww = wg + dw - 1;
                bool ok = ((unsigned)hh < 96u) && ((unsigned)ww < 96u) && (khw < 9);
                const u16* src = XtB + ((size_t)hh * 96 + ww) * 16 + ci0;
                bR1 = ok ? *(const short8*)src : z8;
            }
        }
    };
    auto commit = [&](int buf) {
        *(short8*)(&As[buf][p * LDB + o_lo * 8]) = aR0;
        *(short8*)(&As[buf][p * LDB + (o_lo + 2) * 8]) = aR1;
        *(short8*)(&Bs[buf][p * LDB + o_lo * 8]) = bR0;
        *(short8*)(&Bs[buf][p * LDB + (o_lo + 2) * 8]) = bR1;
    };

    f32x4 acc[4][4];
    f32x4 zz = {0.f, 0.f, 0.f, 0.f};
#pragma unroll
    for (int i = 0; i < 4; i++)
#pragma unroll
        for (int j = 0; j < 4; j++) acc[i][j] = zz;

    // prologue
    stage(0);
    commit(0);
    __syncthreads();

    for (int kt = 0; kt < KTILES; ++kt) {
        int cur = kt & 1;
        if (kt + 1 < KTILES) stage(kt + 1);           // loads in flight
        short8 af[4], bfr[4];
#pragma unroll
        for (int i = 0; i < 4; i++)
            af[i] = *(const short8*)(&As[cur][(wm + i * 16 + r) * LDB + quad * 8]);
#pragma unroll
        for (int j = 0; j < 4; j++)
            bfr[j] = *(const short8*)(&Bs[cur][(wn + j * 16 + r) * LDB + quad * 8]);
#pragma unroll
        for (int i = 0; i < 4; i++)
#pragma unroll
            for (int j = 0; j < 4; j++)
                acc[i][j] = __builtin_amdgcn_mfma_f32_16x16x32_bf16(af[i], bfr[j], acc[i][j], 0, 0, 0);
        if (kt + 1 < KTILES) {
            commit(cur ^ 1);                           // waits vmcnt here, after MFMA
            __syncthreads();
        }
    }

    // ---- epilogue (HW-verified decode): co = wm+i*16+quad*4+g ; pixel = wn+j*16+r
#pragma unroll
    for (int i = 0; i < 4; i++) {
#pragma unroll
        for (int j = 0; j < 4; j++) {
            int pl = wn + j * 16 + r;
            int w = w0 + (pl & 31), h = h0 + (pl >> 5);
#pragma unroll
            for (int g = 0; g < 4; ++g) {
                int co = wm + i * 16 + quad * 4 + g;
                float v = acc[i][j][g];
                size_t oidx = ((size_t)b * 128 + co) * HW + h * 96 + w;
                if constexpr (EPI == 1) {
                    float val = v * invA[co] + betA[co];
                    float sv = val / (1.f + __expf(-val));   // SiLU
                    OutH[oidx] = f2bf(sv);
                } else {
                    float xv = bf2f(xrb[oidx]);
                    float cv = ctxf[oidx];                   // fp32 ctx, same slot
                    float e = __expf(2.f * v);
                    float th = 1.f - 2.f / (e + 1.f);        // tanh
                    OutF[oidx] = xv + cv * (1.f + th);       // fp32 final output
                }
            }
        }
    }
}

// ---------------------------------------------------------------------------
// Per-(batch, token) prep: token = 16x16 mean of xr -> k -> V row, folded A row,
// c0. Grid 64 (b = bid&7, n = bid>>3), 256 threads.
// ---------------------------------------------------------------------------
__global__ __launch_bounds__(256) void prep_attn(
    const u16* __restrict__ xr,
    const float* __restrict__ wk, const float* __restrict__ bk,
    const float* __restrict__ wv, const float* __restrict__ bv,
    const float* __restrict__ wq, const float* __restrict__ bq,
    float* __restrict__ Aout, float* __restrict__ Vout, float* __restrict__ c0out)
{
    __shared__ float part[256];
    __shared__ float tok[128];
    __shared__ float ks[32];
    int t = threadIdx.x;
    int bid = blockIdx.x;
    int b = bid & 7, n = bid >> 3;
    int c = t & 127, half = t >> 7;
    int i0 = (n < 6) ? 0 : 16;
    int j0 = ((n < 6) ? n : (n - 6)) * 16;
    const u16* xb = xr + (size_t)(b * 128 + c) * HW;

    float s = 0.f;
    for (int rr = 0; rr < 8; ++rr) {
        int row = i0 + half * 8 + rr;
        const u16* rp = xb + row * 96 + j0;
        short8 v0 = *(const short8*)rp;
        short8 v1 = *(const short8*)(rp + 8);
#pragma unroll
        for (int j = 0; j < 8; ++j) s += bf2f((u16)v0[j]) + bf2f((u16)v1[j]);
    }
    part[t] = s;
    __syncthreads();
    if (t < 128) tok[t] = (part[t] + part[t + 128]) * (1.f / 256.f);
    __syncthreads();
    if (t < 32) {
        float s2 = bk[t];
        for (int cc = 0; cc < 128; ++cc) s2 += wk[t * 128 + cc] * tok[cc];
        ks[t] = s2;
    }
    __syncthreads();
    if (t < 128) {
        float s3 = bv[c];
        for (int c2 = 0; c2 < 128; ++c2) s3 += wv[c * 128 + c2] * tok[c2];
        Vout[((size_t)b * 8 + n) * 128 + c] = s3;
    } else {
        float s4 = 0.f;
        for (int d = 0; d < 32; ++d) s4 += wq[d * 128 + c] * ks[d];
        Aout[((size_t)b * 8 + n) * 128 + c] = s4;
    }
    if (t == 0) {
        float s5 = 0.f;
        for (int d = 0; d < 32; ++d) s5 += bq[d] * ks[d];
        c0out[b * 8 + n] = s5;
    }
}

// ---------------------------------------------------------------------------
// Fused attention + LocalAtten 1x1 branch. 64 px/block, grid 1152 1-D
// (b = bid&7). ctx -> fp32 d_out; y -> NHWC-16 bf16 (for conv2 staging).
// ---------------------------------------------------------------------------
__global__ __launch_bounds__(256) void attn_k(
    const u16* __restrict__ xr,
    const float* __restrict__ Ain, const float* __restrict__ Vin,
    const float* __restrict__ c0in,
    const float* __restrict__ wla1,
    const float* __restrict__ lag, const float* __restrict__ lab,
    const float* __restrict__ lam, const float* __restrict__ lav,
    float* __restrict__ ctxout, u16* __restrict__ yout)
{
    __shared__ float Xs[128 * 64];       // xr tile, later reused for ctx
    __shared__ float As[8 * 128], Vs[8 * 128], Ws[16 * 128];
    __shared__ float satt[8 * 64];
    __shared__ float c0s[8], inv1[16], bet1[16];

    int t = threadIdx.x;
    int bid = blockIdx.x;
    int b = bid & 7;
    int p0 = (bid >> 3) * 64;

    for (int i = t; i < 1024; i += 256) { As[i] = Ain[b * 1024 + i]; Vs[i] = Vin[b * 1024 + i]; }
    for (int i = t; i < 2048; i += 256) Ws[i] = wla1[i];
    if (t < 8) c0s[t] = c0in[b * 8 + t];
    if (t < 16) {
        float iv = lag[t] * rsqrtf(lav[t] + 1e-5f);
        inv1[t] = iv; bet1[t] = lab[t] - lam[t] * iv;
    }
    const u16* xb = xr + (size_t)b * 128 * HW + p0;
#pragma unroll
    for (int it = 0; it < 4; ++it) {
        int c = (t >> 3) + it * 32;
        int seg = t & 7;
        short8 v = *(const short8*)(xb + (size_t)c * HW + seg * 8);
#pragma unroll
        for (int j = 0; j < 8; ++j) Xs[c * 64 + seg * 8 + j] = bf2f((u16)v[j]);
    }
    __syncthreads();
    {
        int pp = t & 63, ng = t >> 6;
        float a0 = 0.f, a1 = 0.f;
        for (int c = 0; c < 128; ++c) {
            float x = Xs[c * 64 + pp];
            a0 += As[(ng * 2) * 128 + c] * x;
            a1 += As[(ng * 2 + 1) * 128 + c] * x;
        }
        satt[(ng * 2) * 64 + pp] = a0 + c0s[ng * 2];
        satt[(ng * 2 + 1) * 64 + pp] = a1 + c0s[ng * 2 + 1];
    }
    __syncthreads();
    if (t < 64) {
        float m = -1e30f;
        float sv[8];
#pragma unroll
        for (int n = 0; n < 8; ++n) { sv[n] = satt[n * 64 + t]; m = fmaxf(m, sv[n]); }
        float sum = 0.f;
#pragma unroll
        for (int n = 0; n < 8; ++n) { sv[n] = __expf(sv[n] - m); sum += sv[n]; }
        float rcp = 1.f / sum;
#pragma unroll
        for (int n = 0; n < 8; ++n) satt[n * 64 + t] = sv[n] * rcp;
    }
    __syncthreads();
    {
        int pp = t & 63, cg = t >> 6;
        float at[8];
#pragma unroll
        for (int n = 0; n < 8; ++n) at[n] = satt[n * 64 + pp];
        for (int ci = 0; ci < 32; ++ci) {
            int c = cg * 32 + ci;
            float s = 0.f;
#pragma unroll
            for (int n = 0; n < 8; ++n) s += at[n] * Vs[n * 128 + c];
            ctxout[((size_t)b * 128 + c) * HW + p0 + pp] = s;   // fp32
            Xs[c * 64 + pp] = s;
        }
    }
    __syncthreads();
    {
        int pp = t & 63, dg = t >> 6;
        float a[4] = {0.f, 0.f, 0.f, 0.f};
        for (int c = 0; c < 128; ++c) {
            float x = Xs[c * 64 + pp];
#pragma unroll
            for (int k = 0; k < 4; ++k) a[k] += Ws[(dg * 4 + k) * 128 + c] * x;
        }
        s16x4 pk;
#pragma unroll
        for (int k = 0; k < 4; ++k) {
            int d = dg * 4 + k;
            float val = a[k] * inv1[d] + bet1[d];
            float s = val / (1.f + __expf(-val));
            pk[k] = (short)f2bf(s);
        }
        // y in NHWC-16: yt[b][p][d]
        *(s16x4*)(yout + ((size_t)b * HW + p0 + pp) * 16 + dg * 4) = pk;
    }
}

// ---------------------------------------------------------------------------
extern "C" void kernel_launch(void* const* d_in, const int* in_sizes, int n_in,
                              void* d_out, int out_size, void* d_ws, size_t ws_size,
                              hipStream_t stream)
{
    const float* x    = (const float*)d_in[0];
    const float* wred = (const float*)d_in[1];
    const float* bng  = (const float*)d_in[2];
    const float* bnb  = (const float*)d_in[3];
    const float* bnm  = (const float*)d_in[4];
    const float* bnv  = (const float*)d_in[5];
    const float* wq   = (const float*)d_in[6];
    const float* bq   = (const float*)d_in[7];
    const float* wk   = (const float*)d_in[8];
    const float* bk   = (const float*)d_in[9];
    const float* wv   = (const float*)d_in[10];
    const float* bv   = (const float*)d_in[11];
    // d_in[12] = lsh: provably unused (permutation-invariance of softmax attention)
    const float* wla1 = (const float*)d_in[13];
    const float* lag  = (const float*)d_in[14];
    const float* lab  = (const float*)d_in[15];
    const float* lam  = (const float*)d_in[16];
    const float* lav  = (const float*)d_in[17];
    const float* wla2 = (const float*)d_in[18];

    char* ws = (char*)d_ws;
    u16*   xr  = (u16*)(ws + 0);            // 18,874,368 B  bf16 CHW
    u16*   yt  = (u16*)(ws + 18874368);     //  2,359,296 B  bf16 NHWC-16
    u16*   Wt1 = (u16*)(ws + 21233664);     //    589,824 B
    u16*   Wt2 = (u16*)(ws + 21823488);     //     40,960 B
    float* Ab  = (float*)(ws + 21864448);   //     32,768 B
    float* Vb  = (float*)(ws + 21897216);   //     32,768 B
    float* c0b = (float*)(ws + 21929984);   //        256 B
    // xt (NHWC-256 bf16, 37,748,736 B) lives in d_out until attn_k overwrites
    // it with fp32 ctx — conv1/prep complete before that (stream-ordered).
    u16*   xt   = (u16*)d_out;
    float* outp = (float*)d_out;

    transform_w<<<dim3(1232), dim3(256), 0, stream>>>(wred, wla2, Wt1, Wt2);

    transpose_x<<<dim3(288), dim3(256), 0, stream>>>(x, xt);

    conv_k<256, 72, 2304, 1><<<dim3(576), dim3(256), 0, stream>>>(
        xt, Wt1, xr, nullptr, bng, bnb, bnm, bnv, nullptr, nullptr);

    prep_attn<<<dim3(64), dim3(256), 0, stream>>>(xr, wk, bk, wv, bv, wq, bq, Ab, Vb, c0b);

    attn_k<<<dim3(1152), dim3(256), 0, stream>>>(
        xr, Ab, Vb, c0b, wla1, lag, lab, lam, lav, outp, yt);

    conv_k<16, 5, 160, 2><<<dim3(576), dim3(256), 0, stream>>>(
        yt, Wt2, nullptr, outp, nullptr, nullptr, nullptr, nullptr, xr, outp);
}